// Round 3
// baseline (292.494 us; speedup 1.0000x reference)
//
#include <hip/hip_runtime.h>

// out[e, i, c] = sum_j inv[e, i, j] * conv[mesh[e, j], c]
// E = 2,000,000, K = 4, C = 3.
// Memory-bound. R1 showed 114 MB over-fetch = write-allocate on `out` +
// conv eviction from per-XCD L2 by the inv/mesh streams. Fix: nontemporal
// loads for streams, nontemporal stores for out, 2 elems/thread for MLP.
// R2 fix: __builtin_nontemporal_* requires native clang vector types,
// not HIP_vector_type structs.

#define BLOCK 256

typedef float vfloat4 __attribute__((ext_vector_type(4)));
typedef int   vint4   __attribute__((ext_vector_type(4)));

__global__ __launch_bounds__(BLOCK) void
elem_matmul_kernel(const float* __restrict__ conv,
                   const int* __restrict__ mesh,
                   const float* __restrict__ inv,
                   float* __restrict__ out,
                   int half, int E) {
    int t = blockIdx.x * blockDim.x + threadIdx.x;
    if (t >= half) return;

    int e0 = t;
    int e1 = t + half;          // E even → always < E, but guard anyway
    const bool has1 = (e1 < E);

    // ---- Phase 1: index loads (both elements, independent) ----
    const vint4* mp = reinterpret_cast<const vint4*>(mesh);
    vint4 idx0 = __builtin_nontemporal_load(mp + e0);
    vint4 idx1 = has1 ? __builtin_nontemporal_load(mp + e1) : idx0;

    // ---- Phase 2: inverse-matrix stream loads (independent of idx) ----
    vfloat4 r[2][4];
    {
        const vfloat4* ip0 = reinterpret_cast<const vfloat4*>(inv) + 4 * (size_t)e0;
#pragma unroll
        for (int j = 0; j < 4; ++j) r[0][j] = __builtin_nontemporal_load(ip0 + j);
    }
    if (has1) {
        const vfloat4* ip1 = reinterpret_cast<const vfloat4*>(inv) + 4 * (size_t)e1;
#pragma unroll
        for (int j = 0; j < 4; ++j) r[1][j] = __builtin_nontemporal_load(ip1 + j);
    }

    // ---- Phase 3: gathers (L2/L3-resident conv), all 8 issued together ----
    const int vs[2][4] = {{idx0.x, idx0.y, idx0.z, idx0.w},
                          {idx1.x, idx1.y, idx1.z, idx1.w}};
    float g[2][4][3];
#pragma unroll
    for (int k = 0; k < 2; ++k) {
#pragma unroll
        for (int j = 0; j < 4; ++j) {
            const float* p = conv + 3 * (size_t)vs[k][j];
            g[k][j][0] = p[0];
            g[k][j][1] = p[1];
            g[k][j][2] = p[2];
        }
    }

    // ---- Phase 4: compute + nontemporal store ----
#pragma unroll
    for (int k = 0; k < 2; ++k) {
        if (k == 1 && !has1) break;
        float o[4][3];
#pragma unroll
        for (int c = 0; c < 3; ++c) {
#pragma unroll
            for (int i = 0; i < 4; ++i) {
                const vfloat4 ri = r[k][i];
                o[i][c] = ri.x * g[k][0][c] + ri.y * g[k][1][c] +
                          ri.z * g[k][2][c] + ri.w * g[k][3][c];
            }
        }
        vfloat4* op = reinterpret_cast<vfloat4*>(out) + 3 * (size_t)(k == 0 ? e0 : e1);
        vfloat4 s0 = {o[0][0], o[0][1], o[0][2], o[1][0]};
        vfloat4 s1 = {o[1][1], o[1][2], o[2][0], o[2][1]};
        vfloat4 s2 = {o[2][2], o[3][0], o[3][1], o[3][2]};
        __builtin_nontemporal_store(s0, op + 0);
        __builtin_nontemporal_store(s1, op + 1);
        __builtin_nontemporal_store(s2, op + 2);
    }
}

extern "C" void kernel_launch(void* const* d_in, const int* in_sizes, int n_in,
                              void* d_out, int out_size, void* d_ws, size_t ws_size,
                              hipStream_t stream) {
    const float* conv = (const float*)d_in[0];   // (N_NODES, 3) f32
    const int* mesh = (const int*)d_in[1];       // (E, 4) i32
    const float* inv = (const float*)d_in[2];    // (E, 4, 4) f32
    float* out = (float*)d_out;                  // (E, 4, 3) f32

    const int E = in_sizes[1] / 4;
    const int half = (E + 1) / 2;
    const int grid = (half + BLOCK - 1) / BLOCK;
    elem_matmul_kernel<<<grid, BLOCK, 0, stream>>>(conv, mesh, inv, out, half, E);
}